// Round 9
// baseline (154.748 us; speedup 1.0000x reference)
//
#include <hip/hip_runtime.h>
#include <cstdint>

typedef _Float16 half8 __attribute__((ext_vector_type(8)));
typedef float f32x4 __attribute__((ext_vector_type(4)));

#define LN_EPS 1e-5f

__device__ __forceinline__ float dot4(float4 a, float4 b) {
  return a.x*b.x + a.y*b.y + a.z*b.z + a.w*b.w;
}

// ============ K1 (k_pre): blocks 0..255 = mask (1 p-row each); 256..2303 = LN stats.
// FROZEN (round-2 verified form).
__global__ __launch_bounds__(256) void k_pre(
    const float* __restrict__ x, const float* __restrict__ few, const float* __restrict__ feb,
    const float* __restrict__ emb_pr, const float* __restrict__ lnp_w, const float* __restrict__ lnp_b,
    const float* __restrict__ prev, const float* __restrict__ W, const float* __restrict__ Wb,
    const float* __restrict__ emb_col, const float* __restrict__ lnc_w, const float* __restrict__ lnc_b,
    float2* __restrict__ stats2, float* __restrict__ mask_f32, _Float16* __restrict__ mask_f16)
{
  __shared__ __align__(16) struct {
    float xin[512];          // [LN(emb_pr[p]) | prev[p]]
    float xq[256];           // x_prompt row
    float sc[256];           // scores
    float wr1[4], wr2[4];
  } sm;

  int t = threadIdx.x, w = t >> 6, lane = t & 63;

  if (blockIdx.x >= 256) {
    // ================= stats role (wave-autonomous) =================
    int bid = blockIdx.x - 256;
    int b = bid >> 3;
    int cg = (bid & 7) * 4 + w;
    int c0 = cg * 8;
    float xv[8];
    #pragma unroll
    for (int j = 0; j < 8; ++j) xv[j] = x[b*256 + c0 + j];
    float s1[8], s2[8];
    #pragma unroll
    for (int j = 0; j < 8; ++j) { s1[j] = 0.f; s2[j] = 0.f; }
    #pragma unroll
    for (int j = 0; j < 8; ++j) {
      float4 fw = ((const float4*)few)[(c0+j)*64 + lane];
      float4 fb = ((const float4*)feb)[(c0+j)*64 + lane];
      float4 v;
      v.x = fmaxf(fb.x + xv[j]*fw.x, 0.f);
      v.y = fmaxf(fb.y + xv[j]*fw.y, 0.f);
      v.z = fmaxf(fb.z + xv[j]*fw.z, 0.f);
      v.w = fmaxf(fb.w + xv[j]*fw.w, 0.f);
      s1[j] += v.x + v.y + v.z + v.w;
      s2[j] += v.x*v.x + v.y*v.y + v.z*v.z + v.w*v.w;
    }
    #pragma unroll
    for (int o = 32; o > 0; o >>= 1) {
      #pragma unroll
      for (int j = 0; j < 8; ++j) { s1[j] += __shfl_xor(s1[j], o); s2[j] += __shfl_xor(s2[j], o); }
    }
    float mu[8], rs[8];
    #pragma unroll
    for (int j = 0; j < 8; ++j) {
      mu[j] = s1[j] * (1.0f/256.0f);
      float var = s2[j] * (1.0f/256.0f) - mu[j]*mu[j];
      rs[j] = rsqrtf(var + LN_EPS);
    }
    float muv = mu[0], rsv = rs[0];
    #pragma unroll
    for (int j = 1; j < 8; ++j) {
      muv = (lane == j) ? mu[j] : muv;
      rsv = (lane == j) ? rs[j] : rsv;
    }
    if (lane < 8) stats2[b*256 + c0 + lane] = make_float2(muv, rsv);
    return;
  }

  // ================= mask role (p = blockIdx.x) =================
  int p = blockIdx.x;
  int q = t & 3, g = t >> 2;

  // P1
  {
    float4 v = ((const float4*)emb_pr)[p*64 + lane];
    float s1 = v.x + v.y + v.z + v.w;
    float s2 = v.x*v.x + v.y*v.y + v.z*v.z + v.w*v.w;
    #pragma unroll
    for (int o = 32; o > 0; o >>= 1) { s1 += __shfl_xor(s1, o); s2 += __shfl_xor(s2, o); }
    float mu = s1 * (1.0f/256.0f);
    float var = s2 * (1.0f/256.0f) - mu*mu;
    float rsv = rsqrtf(var + LN_EPS);
    float4 w4 = ((const float4*)lnp_w)[lane];
    float4 b4 = ((const float4*)lnp_b)[lane];
    float4 y;
    y.x = (v.x-mu)*rsv*w4.x + b4.x;  y.y = (v.y-mu)*rsv*w4.y + b4.y;
    y.z = (v.z-mu)*rsv*w4.z + b4.z;  y.w = (v.w-mu)*rsv*w4.w + b4.w;
    if (w == 0) {
      ((float4*)sm.xin)[lane] = y;
      ((float4*)sm.xin)[64 + lane] = ((const float4*)prev)[p*64 + lane];
    }
  }
  __syncthreads();

  // P2
  {
    float acc[4] = {0.f, 0.f, 0.f, 0.f};
    #pragma unroll 4
    for (int j = 0; j < 32; ++j) {
      int k4 = j*4 + q;
      float4 xv = ((const float4*)sm.xin)[k4];
      #pragma unroll
      for (int pp = 0; pp < 4; ++pp) {
        int d = pp*64 + g;
        float4 wv = ((const float4*)W)[d*128 + k4];
        acc[pp] += dot4(wv, xv);
      }
    }
    #pragma unroll
    for (int pp = 0; pp < 4; ++pp) {
      acc[pp] += __shfl_xor(acc[pp], 1);
      acc[pp] += __shfl_xor(acc[pp], 2);
    }
    if (q == 0) {
      #pragma unroll
      for (int pp = 0; pp < 4; ++pp) {
        int d = pp*64 + g;
        sm.xq[d] = acc[pp] + Wb[d] + emb_pr[p*256 + d];
      }
    }
  }
  __syncthreads();

  // P3
  {
    float s1[4] = {0,0,0,0}, s2[4] = {0,0,0,0};
    #pragma unroll 4
    for (int j = 0; j < 16; ++j) {
      int k4 = j*4 + q;
      #pragma unroll
      for (int pp = 0; pp < 4; ++pp) {
        float4 v = ((const float4*)emb_col)[(pp*64+g)*64 + k4];
        s1[pp] += v.x + v.y + v.z + v.w;
        s2[pp] += v.x*v.x + v.y*v.y + v.z*v.z + v.w*v.w;
      }
    }
    float mu[4], rs[4];
    #pragma unroll
    for (int pp = 0; pp < 4; ++pp) {
      s1[pp] += __shfl_xor(s1[pp], 1);  s1[pp] += __shfl_xor(s1[pp], 2);
      s2[pp] += __shfl_xor(s2[pp], 1);  s2[pp] += __shfl_xor(s2[pp], 2);
      mu[pp] = s1[pp] * (1.0f/256.0f);
      float var = s2[pp] * (1.0f/256.0f) - mu[pp]*mu[pp];
      rs[pp] = rsqrtf(var + LN_EPS);
    }
    float acc[4] = {0.f, 0.f, 0.f, 0.f};
    #pragma unroll 4
    for (int j = 0; j < 16; ++j) {
      int k4 = j*4 + q;
      float4 lw4 = ((const float4*)lnc_w)[k4];
      float4 lb4 = ((const float4*)lnc_b)[k4];
      float4 xv = ((const float4*)sm.xq)[k4];
      #pragma unroll
      for (int pp = 0; pp < 4; ++pp) {
        float4 v = ((const float4*)emb_col)[(pp*64+g)*64 + k4];
        float4 nc;
        nc.x = (v.x-mu[pp])*rs[pp]*lw4.x + lb4.x;
        nc.y = (v.y-mu[pp])*rs[pp]*lw4.y + lb4.y;
        nc.z = (v.z-mu[pp])*rs[pp]*lw4.z + lb4.z;
        nc.w = (v.w-mu[pp])*rs[pp]*lw4.w + lb4.w;
        acc[pp] += dot4(nc, xv);
      }
    }
    #pragma unroll
    for (int pp = 0; pp < 4; ++pp) {
      acc[pp] += __shfl_xor(acc[pp], 1);
      acc[pp] += __shfl_xor(acc[pp], 2);
    }
    if (q == 0) {
      #pragma unroll
      for (int pp = 0; pp < 4; ++pp) sm.sc[pp*64 + g] = acc[pp];
    }
  }
  __syncthreads();

  // P4
  {
    float val = sm.sc[t];
    float m0 = val;
    #pragma unroll
    for (int o = 32; o > 0; o >>= 1) m0 = fmaxf(m0, __shfl_xor(m0, o));
    if (lane == 0) sm.wr1[w] = m0;
    __syncthreads();
    float M = fmaxf(fmaxf(sm.wr1[0], sm.wr1[1]), fmaxf(sm.wr1[2], sm.wr1[3]));
    float e = expf(val - M);
    float s = e;
    #pragma unroll
    for (int o = 32; o > 0; o >>= 1) s += __shfl_xor(s, o);
    if (lane == 0) sm.wr2[w] = s;
    __syncthreads();
    float S = sm.wr2[0] + sm.wr2[1] + sm.wr2[2] + sm.wr2[3];
    float mv = e / S;
    mask_f32[p*256 + t] = mv;
    mask_f16[p*256 + t] = (_Float16)mv;
  }
}

// ============ K2 (k_main) v6: 2 BATCHES PER BLOCK — amortize shared operands.
// few/feb and mask are b-independent: block = (b0,b1) x one 64-d slab. few/feb
// read ONCE for both producers; every mask fragment feeds TWO accumulations.
// Shared-operand L2 traffic halves (262->134 MB); grid 512 = exactly 2 blocks/CU
// (70 KB LDS), all resident. Barrier-minimal v5 schedule kept (2 barriers).
// Nontemporal epilogue stores keep the 67 MB write stream from evicting the hot
// few/feb/mask L2 lines. All fragment maps / LDS layout / epilogue math verbatim.
__global__ __launch_bounds__(256) void k_main(
    const float* __restrict__ x, const float* __restrict__ few, const float* __restrict__ feb,
    const float* __restrict__ ln_emb_w, const float* __restrict__ ln_emb_b,
    const float2* __restrict__ stats2,
    const _Float16* __restrict__ mask_f16, const float* __restrict__ mask_f32,
    const float* __restrict__ ew, const float* __restrict__ eb,
    float* __restrict__ out)
{
  __shared__ __align__(16) _Float16 Bs0[4 * 8 * 64 * 8];   // 32 KB, [kb][k8][n=64][8]
  __shared__ __align__(16) _Float16 Bs1[4 * 8 * 64 * 8];   // 32 KB
  __shared__ float xrow0[256], xrow1[256];
  __shared__ __align__(8) float2 srow0[256], srow1[256];

  const int t = threadIdx.x, w = t >> 6, lane = t & 63;
  const int lm = lane & 15, quad = lane >> 4;
  const int b0 = (blockIdx.x >> 2) << 1, b1 = b0 + 1;
  const int ds = (blockIdx.x & 3) * 64;
  const int dl = t & 63;
  const int d  = ds + dl;

  xrow0[t] = x[b0*256 + t];
  xrow1[t] = x[b1*256 + t];
  srow0[t] = stats2[b0*256 + t];
  srow1[t] = stats2[b1*256 + t];
  const float lwv = ln_emb_w[d];
  const float lbv = ln_emb_b[d];

  f32x4 accA[4][4], accB[4][4];
  #pragma unroll
  for (int i = 0; i < 4; ++i)
    #pragma unroll
    for (int j = 0; j < 4; ++j) {
      accA[i][j] = (f32x4){0.f, 0.f, 0.f, 0.f};
      accB[i][j] = (f32x4){0.f, 0.f, 0.f, 0.f};
    }

  __syncthreads();              // barrier 1: xrow/srow visible

  // producer sweep: all 256 c, both b, one fw/fb read per (c,d) serving both.
  #pragma unroll
  for (int kb = 0; kb < 4; ++kb) {
    half8 hA0, hA1, hB0, hB1;
    #pragma unroll
    for (int j = 0; j < 16; ++j) {
      int cl = kb*64 + w*16 + j;
      float fw = few[cl*256 + d];
      float fb = feb[cl*256 + d];
      float2 s0 = srow0[cl];
      float2 s1 = srow1[cl];
      float v0 = fmaxf(fb + xrow0[cl]*fw, 0.f);
      float v1 = fmaxf(fb + xrow1[cl]*fw, 0.f);
      _Float16 h0 = (_Float16)((v0 - s0.x) * s0.y * lwv + lbv);
      _Float16 h1 = (_Float16)((v1 - s1.x) * s1.y * lwv + lbv);
      if (j < 8) { hA0[j] = h0; hB0[j] = h1; }
      else       { hA1[j-8] = h0; hB1[j-8] = h1; }
    }
    *(half8*)(&Bs0[((kb*8 + w*2 + 0)*64 + dl)*8]) = hA0;
    *(half8*)(&Bs0[((kb*8 + w*2 + 1)*64 + dl)*8]) = hA1;
    *(half8*)(&Bs1[((kb*8 + w*2 + 0)*64 + dl)*8]) = hB0;
    *(half8*)(&Bs1[((kb*8 + w*2 + 1)*64 + dl)*8]) = hB1;
  }
  __syncthreads();              // barrier 2: Bs0/Bs1 ready

  // MFMA sweep: zero barriers; each mask fragment feeds both accA and accB.
  #pragma unroll
  for (int kb = 0; kb < 4; ++kb) {
    half8 mf[2][4];
    #pragma unroll
    for (int ks = 0; ks < 2; ++ks)
      #pragma unroll
      for (int nt = 0; nt < 4; ++nt)
        mf[ks][nt] = *(const half8*)(mask_f16 + (size_t)(w*64 + nt*16 + lm)*256 + kb*64 + ks*32 + quad*8);
    #pragma unroll
    for (int ks = 0; ks < 2; ++ks) {
      half8 xf0[4], xf1[4];
      #pragma unroll
      for (int mt = 0; mt < 4; ++mt) {
        xf0[mt] = *(const half8*)(&Bs0[((kb*8 + ks*4 + quad)*64 + mt*16 + lm)*8]);
        xf1[mt] = *(const half8*)(&Bs1[((kb*8 + ks*4 + quad)*64 + mt*16 + lm)*8]);
      }
      #pragma unroll
      for (int mt = 0; mt < 4; ++mt)
        #pragma unroll
        for (int nt = 0; nt < 4; ++nt) {
          accA[mt][nt] = __builtin_amdgcn_mfma_f32_16x16x32_f16(xf0[mt], mf[ks][nt], accA[mt][nt], 0, 0, 0);
          accB[mt][nt] = __builtin_amdgcn_mfma_f32_16x16x32_f16(xf1[mt], mf[ks][nt], accB[mt][nt], 0, 0, 0);
        }
    }
  }

  // epilogue: acc[mt][nt] -> row d = ds + mt*16 + quad*4 + r, col p = w*64+nt*16+lm;
  // nontemporal float4 stores along d.
  {
    const float ebv = eb[b0];
    float sp[4], tb[4];
    #pragma unroll
    for (int nt = 0; nt < 4; ++nt) {
      int p = w*64 + nt*16 + lm;
      sp[nt] = 1.0f + ew[p];
      tb[nt] = mask_f32[b0*256 + p] * ebv;
    }
    #pragma unroll
    for (int mt = 0; mt < 4; ++mt)
      #pragma unroll
      for (int nt = 0; nt < 4; ++nt) {
        int p = w*64 + nt*16 + lm;
        int dd = ds + mt*16 + quad*4;
        f32x4 o = accA[mt][nt] * sp[nt] + tb[nt];
        __builtin_nontemporal_store(o, (f32x4*)(out + ((size_t)b0 << 16) + ((size_t)p << 8) + dd));
      }
  }
  {
    const float ebv = eb[b1];
    float sp[4], tb[4];
    #pragma unroll
    for (int nt = 0; nt < 4; ++nt) {
      int p = w*64 + nt*16 + lm;
      sp[nt] = 1.0f + ew[p];
      tb[nt] = mask_f32[b1*256 + p] * ebv;
    }
    #pragma unroll
    for (int mt = 0; mt < 4; ++mt)
      #pragma unroll
      for (int nt = 0; nt < 4; ++nt) {
        int p = w*64 + nt*16 + lm;
        int dd = ds + mt*16 + quad*4;
        f32x4 o = accB[mt][nt] * sp[nt] + tb[nt];
        __builtin_nontemporal_store(o, (f32x4*)(out + ((size_t)b1 << 16) + ((size_t)p << 8) + dd));
      }
  }
}

extern "C" void kernel_launch(void* const* d_in, const int* in_sizes, int n_in,
                              void* d_out, int out_size, void* d_ws, size_t ws_size,
                              hipStream_t stream) {
  const float* x        = (const float*)d_in[0];
  const float* prev     = (const float*)d_in[1];
  const float* few      = (const float*)d_in[2];
  const float* feb      = (const float*)d_in[3];
  const float* ln_emb_w = (const float*)d_in[4];
  const float* ln_emb_b = (const float*)d_in[5];
  const float* ln_col_w = (const float*)d_in[6];
  const float* ln_col_b = (const float*)d_in[7];
  const float* ln_pr_w  = (const float*)d_in[8];
  const float* ln_pr_b  = (const float*)d_in[9];
  const float* dimp_w   = (const float*)d_in[10];
  const float* dimp_b   = (const float*)d_in[11];
  const float* emb_col  = (const float*)d_in[12];
  const float* emb_pr   = (const float*)d_in[13];
  const float* ew       = (const float*)d_in[14];
  const float* eb       = (const float*)d_in[15];
  float* out = (float*)d_out;

  char* wsb = (char*)d_ws;
  float2*   ws_stats  = (float2*)(wsb);                  // 524,288 B
  float*    ws_mask   = (float*)(wsb + 524288);          // 262,144 B
  _Float16* ws_mask_h = (_Float16*)(wsb + 786432);       // 131,072 B

  k_pre<<<dim3(256 + 2048), dim3(256), 0, stream>>>(
      x, few, feb,
      emb_pr, ln_pr_w, ln_pr_b, prev, dimp_w, dimp_b,
      emb_col, ln_col_w, ln_col_b,
      ws_stats, ws_mask, ws_mask_h);
  k_main<<<dim3(512), dim3(256), 0, stream>>>(
      x, few, feb, ln_emb_w, ln_emb_b,
      ws_stats, ws_mask_h, ws_mask, ew, eb, out);
}